// Round 1
// baseline (2442.015 us; speedup 1.0000x reference)
//
#include <hip/hip_runtime.h>

#define B_   16
#define T_   2048
#define DM_  512
#define DH_  64
#define NTOK (B_ * T_)

// ---------------------------------------------------------------------------
// Kernel 1: fused projection.  qkv[bt][0:64]=q, [64:128]=k, [128:192]=v
// C[32768 x 192] = X[32768 x 512] * W^T, tiled 64 tok x 192 out x BK=32.
// ---------------------------------------------------------------------------
__global__ __launch_bounds__(256) void proj_kernel(
    const float* __restrict__ x,
    const float* __restrict__ Wq, const float* __restrict__ bq,
    const float* __restrict__ Wk, const float* __restrict__ bk,
    const float* __restrict__ Wv, const float* __restrict__ bvp,
    float* __restrict__ qkv)
{
    __shared__ __align__(16) float xs[32][64];    // [k][tok]
    __shared__ __align__(16) float ws[32][192];   // [k][d]
    const int tid = threadIdx.x;
    const int bt0 = blockIdx.x * 64;
    const int ty  = tid >> 4;   // 0..15  -> tokens ty*4 .. ty*4+3
    const int tx  = tid & 15;   // 0..15  -> cols   tx*12 .. tx*12+11

    float acc[4][12];
#pragma unroll
    for (int i = 0; i < 4; i++)
#pragma unroll
        for (int j = 0; j < 12; j++) acc[i][j] = 0.f;

    for (int kb = 0; kb < DM_; kb += 32) {
        // stage x tile, transposed to [k][tok]
#pragma unroll
        for (int r = 0; r < 2; r++) {
            int idx = tid + r * 256;           // 0..511 float4s
            int tok = idx >> 3, kq = idx & 7;
            float4 xv = *(const float4*)&x[(size_t)(bt0 + tok) * DM_ + kb + kq * 4];
            xs[kq * 4 + 0][tok] = xv.x;
            xs[kq * 4 + 1][tok] = xv.y;
            xs[kq * 4 + 2][tok] = xv.z;
            xs[kq * 4 + 3][tok] = xv.w;
        }
        // stage W tile, rows 0-63 = Wq, 64-127 = Wk, 128-191 = Wv, transposed to [k][d]
#pragma unroll
        for (int r = 0; r < 6; r++) {
            int idx = tid + r * 256;           // 0..1535 float4s
            int d = idx >> 3, kq = idx & 7;
            const float* wrow = (d < 64)  ? (Wq + (size_t)d * DM_)
                              : (d < 128) ? (Wk + (size_t)(d - 64) * DM_)
                                          : (Wv + (size_t)(d - 128) * DM_);
            float4 wv4 = *(const float4*)&wrow[kb + kq * 4];
            ws[kq * 4 + 0][d] = wv4.x;
            ws[kq * 4 + 1][d] = wv4.y;
            ws[kq * 4 + 2][d] = wv4.z;
            ws[kq * 4 + 3][d] = wv4.w;
        }
        __syncthreads();

#pragma unroll
        for (int kk = 0; kk < 32; kk++) {
            float4 x4 = *(const float4*)&xs[kk][ty * 4];
            float4 wa = *(const float4*)&ws[kk][tx * 12];
            float4 wb = *(const float4*)&ws[kk][tx * 12 + 4];
            float4 wc = *(const float4*)&ws[kk][tx * 12 + 8];
            const float xv[4]  = {x4.x, x4.y, x4.z, x4.w};
            const float wv[12] = {wa.x, wa.y, wa.z, wa.w,
                                  wb.x, wb.y, wb.z, wb.w,
                                  wc.x, wc.y, wc.z, wc.w};
#pragma unroll
            for (int i = 0; i < 4; i++)
#pragma unroll
                for (int j = 0; j < 12; j++)
                    acc[i][j] = fmaf(xv[i], wv[j], acc[i][j]);
        }
        __syncthreads();
    }

#pragma unroll
    for (int i = 0; i < 4; i++) {
        const int bt = bt0 + ty * 4 + i;
        float* dst = qkv + (size_t)bt * 192 + tx * 12;
#pragma unroll
        for (int j = 0; j < 12; j++) {
            int c = tx * 12 + j;
            float bias = (c < 64) ? bq[c] : (c < 128) ? bk[c - 64] : bvp[c - 128];
            dst[j] = acc[i][j] + bias;
        }
    }
}

// ---------------------------------------------------------------------------
// Kernel 2: sequential scan.  1 block per batch, 2 waves.
//   wave 0: lane i owns row i of A (64 regs) and row i of S (64 regs).
//   wave 1: producer, double-buffers the next 32-step qkv tile into LDS.
// Uses z_t = A_{t-1} u_t / denom_t  (Sherman-Morrison identity) to avoid
// the second matvec the reference does.
// ---------------------------------------------------------------------------
__global__ __launch_bounds__(128) void scan_kernel(
    const float* __restrict__ qkv, float* __restrict__ O)
{
    __shared__ __align__(16) float stage[2][32 * 192];  // 2 x 24KB
    __shared__ __align__(16) float au_s[64];
    const int tid  = threadIdx.x;
    const int lane = tid & 63;
    const int w    = tid >> 6;
    const int b    = blockIdx.x;
    const float* src = qkv + (size_t)b * T_ * 192;
    float* Og = O + (size_t)b * T_ * DH_;

    float A[64], S[64];
#pragma unroll
    for (int j = 0; j < 64; j++) {
        A[j] = (j == lane) ? 1.f : 0.f;   // A0 = I / lambda_0, lambda_0 = 1
        S[j] = 0.f;
    }

    if (w == 1) {  // prologue: stage block 0
#pragma unroll 2
        for (int r = 0; r < 24; r++)
            *(float4*)&stage[0][r * 256 + lane * 4] =
                *(const float4*)&src[r * 256 + lane * 4];
    }
    __syncthreads();

    for (int blk = 0; blk < 64; ++blk) {
        const int buf = blk & 1;
        if (w == 1) {
            if (blk + 1 < 64) {
                const float* s2 = src + (size_t)(blk + 1) * 6144;
                float* dst = &stage[buf ^ 1][0];
#pragma unroll 2
                for (int r = 0; r < 24; r++)
                    *(float4*)&dst[r * 256 + lane * 4] =
                        *(const float4*)&s2[r * 256 + lane * 4];
            }
        } else {
            float* Ob = Og + (size_t)blk * 32 * DH_;
            for (int tt = 0; tt < 32; ++tt) {
                const float* st = &stage[buf][tt * 192];
                const float ql = st[lane];
                const float kl = st[64 + lane];
                const float vl = st[128 + lane];

                // s = q . k  (full-wave reduce; overlaps with Au matvec)
                float red = ql * kl;
#pragma unroll
                for (int off = 32; off; off >>= 1) red += __shfl_xor(red, off, 64);
                const float s = red;

                // Au[i] = sum_j A[i][j] * k[j]   (k broadcast from LDS stage)
                float au0 = 0.f, au1 = 0.f, au2 = 0.f, au3 = 0.f;
#pragma unroll
                for (int jj = 0; jj < 16; jj++) {
                    const float4 k4 = *(const float4*)&st[64 + jj * 4];
                    au0 = fmaf(A[4 * jj + 0], k4.x, au0);
                    au1 = fmaf(A[4 * jj + 1], k4.y, au1);
                    au2 = fmaf(A[4 * jj + 2], k4.z, au2);
                    au3 = fmaf(A[4 * jj + 3], k4.w, au3);
                }
                const float Au = (au0 + au1) + (au2 + au3);
                au_s[lane] = Au;                     // broadcast Au (same-wave DS, in-order)

                float red2 = kl * Au;                // denom = 1 + k . Au
#pragma unroll
                for (int off = 32; off; off >>= 1) red2 += __shfl_xor(red2, off, 64);
                const float rinv = 1.0f / (1.0f + red2);
                asm volatile("" ::: "memory");       // keep au_s write before reads

                const float ci  = Au * rinv;          // A[i][j] -= Au_i*Au_j/denom
                const float vsa = vl * (s * rinv);    // S[i][j] += v_i * (s*Au_j/denom)
                float o0 = 0.f, o1 = 0.f, o2 = 0.f, o3 = 0.f;
#pragma unroll
                for (int jj = 0; jj < 16; jj++) {
                    const float4 a4 = *(const float4*)&au_s[4 * jj];
                    const float4 q4 = *(const float4*)&st[4 * jj];
                    A[4 * jj + 0] = fmaf(-ci, a4.x, A[4 * jj + 0]);
                    S[4 * jj + 0] = fmaf(vsa, a4.x, S[4 * jj + 0]);
                    o0 = fmaf(S[4 * jj + 0], q4.x, o0);
                    A[4 * jj + 1] = fmaf(-ci, a4.y, A[4 * jj + 1]);
                    S[4 * jj + 1] = fmaf(vsa, a4.y, S[4 * jj + 1]);
                    o1 = fmaf(S[4 * jj + 1], q4.y, o1);
                    A[4 * jj + 2] = fmaf(-ci, a4.z, A[4 * jj + 2]);
                    S[4 * jj + 2] = fmaf(vsa, a4.z, S[4 * jj + 2]);
                    o2 = fmaf(S[4 * jj + 2], q4.z, o2);
                    A[4 * jj + 3] = fmaf(-ci, a4.w, A[4 * jj + 3]);
                    S[4 * jj + 3] = fmaf(vsa, a4.w, S[4 * jj + 3]);
                    o3 = fmaf(S[4 * jj + 3], q4.w, o3);
                }
                Ob[tt * DH_ + lane] = (o0 + o1) + (o2 + o3);
            }
        }
        __syncthreads();
    }
}

// ---------------------------------------------------------------------------
// Kernel 3: out[bt][m] = sum_d O[bt][d] * Wo[m][d] + bo[m]
// block = 16 tokens x 512 m; thread owns m = 2*tid.
// ---------------------------------------------------------------------------
__global__ __launch_bounds__(256) void oproj_kernel(
    const float* __restrict__ O, const float* __restrict__ Wo,
    const float* __restrict__ bo, float* __restrict__ out)
{
    __shared__ __align__(16) float os[16][64];
    const int tid = threadIdx.x;
    const size_t t0 = (size_t)blockIdx.x * 16;
    {
        int tok = tid >> 4, dq = tid & 15;
        *(float4*)&os[tok][dq * 4] = *(const float4*)&O[(t0 + tok) * 64 + dq * 4];
    }
    __syncthreads();

    const int m = tid * 2;
    float acc0[16], acc1[16];
#pragma unroll
    for (int i = 0; i < 16; i++) { acc0[i] = 0.f; acc1[i] = 0.f; }

    const float* w0 = Wo + (size_t)m * 64;
    const float* w1 = w0 + 64;
#pragma unroll
    for (int dq = 0; dq < 16; ++dq) {
        float4 wa = *(const float4*)&w0[dq * 4];
        float4 wb = *(const float4*)&w1[dq * 4];
#pragma unroll
        for (int tok = 0; tok < 16; ++tok) {
            float4 o4 = *(const float4*)&os[tok][dq * 4];   // broadcast read
            acc0[tok] = fmaf(o4.x, wa.x, fmaf(o4.y, wa.y,
                        fmaf(o4.z, wa.z, fmaf(o4.w, wa.w, acc0[tok]))));
            acc1[tok] = fmaf(o4.x, wb.x, fmaf(o4.y, wb.y,
                        fmaf(o4.z, wb.z, fmaf(o4.w, wb.w, acc1[tok]))));
        }
    }
    const float b0 = bo[m], b1 = bo[m + 1];
#pragma unroll
    for (int tok = 0; tok < 16; ++tok) {
        float2 v = make_float2(acc0[tok] + b0, acc1[tok] + b1);
        *(float2*)&out[(t0 + tok) * DM_ + m] = v;
    }
}

// ---------------------------------------------------------------------------
extern "C" void kernel_launch(void* const* d_in, const int* in_sizes, int n_in,
                              void* d_out, int out_size, void* d_ws, size_t ws_size,
                              hipStream_t stream)
{
    const float* x  = (const float*)d_in[0];
    const float* Wq = (const float*)d_in[1];
    const float* bq = (const float*)d_in[2];
    const float* Wk = (const float*)d_in[3];
    const float* bk = (const float*)d_in[4];
    const float* Wv = (const float*)d_in[5];
    const float* bv = (const float*)d_in[6];
    const float* Wo = (const float*)d_in[7];
    const float* bo = (const float*)d_in[8];
    float* out = (float*)d_out;

    // workspace layout: qkv [NTOK*192] fp32, then O [NTOK*64] fp32 (~33.5 MB)
    float* qkv = (float*)d_ws;
    float* O   = qkv + (size_t)NTOK * 192;

    proj_kernel<<<NTOK / 64, 256, 0, stream>>>(x, Wq, bq, Wk, bk, Wv, bv, qkv);
    scan_kernel<<<B_, 128, 0, stream>>>(qkv, O);
    oproj_kernel<<<NTOK / 16, 256, 0, stream>>>(O, Wo, bo, out);
}

// Round 2
// 1969.885 us; speedup vs baseline: 1.2397x; 1.2397x over previous
//
#include <hip/hip_runtime.h>

#define B_   16
#define T_   2048
#define DM_  512
#define DH_  64
#define NTOK (B_ * T_)

typedef float f32x2 __attribute__((ext_vector_type(2)));
typedef float f32x4 __attribute__((ext_vector_type(4)));

// ---------------------------------------------------------------------------
// Kernel 1: fused projection.  qkv[bt][0:64]=q, [64:128]=k, [128:192]=v
// ---------------------------------------------------------------------------
__global__ __launch_bounds__(256) void proj_kernel(
    const float* __restrict__ x,
    const float* __restrict__ Wq, const float* __restrict__ bq,
    const float* __restrict__ Wk, const float* __restrict__ bk,
    const float* __restrict__ Wv, const float* __restrict__ bvp,
    float* __restrict__ qkv)
{
    __shared__ __align__(16) float xs[32][64];    // [k][tok]
    __shared__ __align__(16) float ws[32][192];   // [k][d]
    const int tid = threadIdx.x;
    const int bt0 = blockIdx.x * 64;
    const int ty  = tid >> 4;   // 0..15  -> tokens ty*4 .. ty*4+3
    const int tx  = tid & 15;   // 0..15  -> cols   tx*12 .. tx*12+11

    f32x2 acc2[4][6];
#pragma unroll
    for (int i = 0; i < 4; i++)
#pragma unroll
        for (int j = 0; j < 6; j++) acc2[i][j] = (f32x2){0.f, 0.f};

    for (int kb = 0; kb < DM_; kb += 32) {
#pragma unroll
        for (int r = 0; r < 2; r++) {
            int idx = tid + r * 256;
            int tok = idx >> 3, kq = idx & 7;
            f32x4 xv = *(const f32x4*)&x[(size_t)(bt0 + tok) * DM_ + kb + kq * 4];
            xs[kq * 4 + 0][tok] = xv.x;
            xs[kq * 4 + 1][tok] = xv.y;
            xs[kq * 4 + 2][tok] = xv.z;
            xs[kq * 4 + 3][tok] = xv.w;
        }
#pragma unroll
        for (int r = 0; r < 6; r++) {
            int idx = tid + r * 256;
            int d = idx >> 3, kq = idx & 7;
            const float* wrow = (d < 64)  ? (Wq + (size_t)d * DM_)
                              : (d < 128) ? (Wk + (size_t)(d - 64) * DM_)
                                          : (Wv + (size_t)(d - 128) * DM_);
            f32x4 wv4 = *(const f32x4*)&wrow[kb + kq * 4];
            ws[kq * 4 + 0][d] = wv4.x;
            ws[kq * 4 + 1][d] = wv4.y;
            ws[kq * 4 + 2][d] = wv4.z;
            ws[kq * 4 + 3][d] = wv4.w;
        }
        __syncthreads();

#pragma unroll
        for (int kk = 0; kk < 32; kk++) {
            f32x4 x4 = *(const f32x4*)&xs[kk][ty * 4];
            const float xv[4] = {x4.x, x4.y, x4.z, x4.w};
            const f32x2* wsp = (const f32x2*)&ws[kk][tx * 12];
            f32x2 w2[6];
#pragma unroll
            for (int j2 = 0; j2 < 6; j2++) w2[j2] = wsp[j2];
#pragma unroll
            for (int i = 0; i < 4; i++) {
                f32x2 xb = {xv[i], xv[i]};
#pragma unroll
                for (int j2 = 0; j2 < 6; j2++)
                    acc2[i][j2] = __builtin_elementwise_fma(xb, w2[j2], acc2[i][j2]);
            }
        }
        __syncthreads();
    }

#pragma unroll
    for (int i = 0; i < 4; i++) {
        const int bt = bt0 + ty * 4 + i;
        float* dst = qkv + (size_t)bt * 192 + tx * 12;
#pragma unroll
        for (int j2 = 0; j2 < 6; j2++) {
            int c0 = tx * 12 + 2 * j2;
#pragma unroll
            for (int h = 0; h < 2; h++) {
                int c = c0 + h;
                float bias = (c < 64) ? bq[c] : (c < 128) ? bk[c - 64] : bvp[c - 128];
                dst[2 * j2 + h] = ((h == 0) ? acc2[i][j2].x : acc2[i][j2].y) + bias;
            }
        }
    }
}

// ---------------------------------------------------------------------------
// Kernel 1b: s[t] = q_t . k_t   (8 lanes per token)
// ---------------------------------------------------------------------------
__global__ __launch_bounds__(256) void sdot_kernel(
    const float* __restrict__ qkv, float* __restrict__ sbuf)
{
    const int tid = blockIdx.x * 256 + threadIdx.x;
    const int tok = tid >> 3, l = tid & 7;
    const float* row = qkv + (size_t)tok * 192 + l * 8;
    f32x4 qa = *(const f32x4*)row;
    f32x4 qb = *(const f32x4*)(row + 4);
    f32x4 ka = *(const f32x4*)(row + 64);
    f32x4 kb = *(const f32x4*)(row + 68);
    float r = qa.x * ka.x + qa.y * ka.y + qa.z * ka.z + qa.w * ka.w
            + qb.x * kb.x + qb.y * kb.y + qb.z * kb.z + qb.w * kb.w;
    r += __shfl_xor(r, 1, 64);
    r += __shfl_xor(r, 2, 64);
    r += __shfl_xor(r, 4, 64);
    if (l == 0) sbuf[tok] = r;
}

// ---------------------------------------------------------------------------
// Kernel 2: sequential scan, deferred-update form.
//   wave 0 computes; wave 1 double-buffers qkv+s tiles.
// Per step t (all updates from step t-1 folded in):
//   Loop1: A[j] -= ci_prev*au_prev[j]  (fold) ; y_i += A[i][j]*k_j
//   reduce (packed): rd = k.y, rq = q.y        (overlapped with Loop2)
//   Loop2: S[j] -= ... fold vsa_prev*au_prev[j]; o'_i += S[i][j]*q_j
//   rinv = 1/(1+rd); o_i = o'_i + s*rinv*rq*v_i; ci=y_i*rinv; vsa=v_i*s*rinv
// ---------------------------------------------------------------------------
__global__ __launch_bounds__(128, 1) void scan_kernel(
    const float* __restrict__ qkv, const float* __restrict__ sbuf,
    float* __restrict__ O)
{
    __shared__ __align__(16) float stage[2][32 * 192];  // 2 x 24KB
    __shared__ __align__(16) float sst[2][32];
    __shared__ __align__(16) float au_sm[2][64];
    const int tid  = threadIdx.x;
    const int lane = tid & 63;
    const int w    = tid >> 6;
    const int b    = blockIdx.x;
    const float* src = qkv + (size_t)b * T_ * 192;
    const float* sb  = sbuf + (size_t)b * T_;
    float* Og = O + (size_t)b * T_ * DH_;

    if (w == 1) {  // prologue: stage block 0
#pragma unroll 2
        for (int r = 0; r < 24; r++)
            *(f32x4*)&stage[0][r * 256 + lane * 4] =
                *(const f32x4*)&src[r * 256 + lane * 4];
        if (lane < 8) ((f32x4*)sst[0])[lane] = ((const f32x4*)sb)[lane];
    } else {
        au_sm[0][lane] = 0.f;   // avoid NaN garbage in first fold
        au_sm[1][lane] = 0.f;
    }
    __syncthreads();

    if (w == 1) {
        for (int blk = 0; blk < 64; ++blk) {
            if (blk + 1 < 64) {
                const float* s2 = src + (size_t)(blk + 1) * 6144;
                float* dst = stage[(blk + 1) & 1];
#pragma unroll 2
                for (int r = 0; r < 24; r++)
                    *(f32x4*)&dst[r * 256 + lane * 4] =
                        *(const f32x4*)&s2[r * 256 + lane * 4];
                if (lane < 8)
                    ((f32x4*)sst[(blk + 1) & 1])[lane] =
                        ((const f32x4*)(sb + (size_t)(blk + 1) * 32))[lane];
            }
            __syncthreads();
        }
    } else {
        f32x2 A2[32], S2[32];
#pragma unroll
        for (int m = 0; m < 32; m++) {
            A2[m].x = (2 * m == lane)     ? 1.f : 0.f;   // A0 = I
            A2[m].y = (2 * m + 1 == lane) ? 1.f : 0.f;
            S2[m] = (f32x2){0.f, 0.f};
        }
        float ci = 0.f, vsa = 0.f;

        for (int blk = 0; blk < 64; ++blk) {
            const float* stg = stage[blk & 1];
            const float* ss  = sst[blk & 1];
            float* Ob = Og + (size_t)blk * 32 * DH_;
            for (int tt = 0; tt < 32; ++tt) {
                const float* st = stg + tt * 192;
                const int cb = tt & 1;
                const float* aup = au_sm[cb ^ 1];   // au of step t-1
                const float ql = st[lane];
                const float kl = st[64 + lane];
                const float vl = st[128 + lane];
                const float s  = ss[tt];
                const f32x2 nci2 = {-ci, -ci};

                // Loop1: fold A-update(t-1), compute y = A_{t-1} k_t
                f32x2 y0 = {0,0}, y1 = {0,0}, y2a = {0,0}, y3 = {0,0};
#pragma unroll
                for (int jj = 0; jj < 16; jj++) {
                    f32x4 k4 = *(const f32x4*)&st[64 + jj * 4];
                    f32x4 a4 = *(const f32x4*)&aup[jj * 4];
                    f32x2 k2a = {k4.x, k4.y}, k2b = {k4.z, k4.w};
                    f32x2 a2a = {a4.x, a4.y}, a2b = {a4.z, a4.w};
                    A2[2*jj]   = __builtin_elementwise_fma(nci2, a2a, A2[2*jj]);
                    A2[2*jj+1] = __builtin_elementwise_fma(nci2, a2b, A2[2*jj+1]);
                    if (jj & 1) {
                        y1 = __builtin_elementwise_fma(A2[2*jj],   k2a, y1);
                        y3 = __builtin_elementwise_fma(A2[2*jj+1], k2b, y3);
                    } else {
                        y0  = __builtin_elementwise_fma(A2[2*jj],   k2a, y0);
                        y2a = __builtin_elementwise_fma(A2[2*jj+1], k2b, y2a);
                    }
                }
                f32x2 ys = (y0 + y1) + (y2a + y3);
                const float y = ys.x + ys.y;
                au_sm[cb][lane] = y;

                // packed cross-lane reduce: rd = k.y, rq = q.y (two chains, ILP)
                float rd = kl * y, rq = ql * y;
#pragma unroll
                for (int off = 32; off; off >>= 1) {
                    rd += __shfl_xor(rd, off, 64);
                    rq += __shfl_xor(rq, off, 64);
                }

                // Loop2: fold S-update(t-1), compute o' = S_{t-1} q_t
                // (independent of rd/rq -> hides the shfl latency)
                const f32x2 vsa2 = {vsa, vsa};
                f32x2 o0 = {0,0}, o1 = {0,0}, o2v = {0,0}, o3 = {0,0};
#pragma unroll
                for (int jj = 0; jj < 16; jj++) {
                    f32x4 q4 = *(const f32x4*)&st[jj * 4];
                    f32x4 a4 = *(const f32x4*)&aup[jj * 4];
                    f32x2 q2a = {q4.x, q4.y}, q2b = {q4.z, q4.w};
                    f32x2 a2a = {a4.x, a4.y}, a2b = {a4.z, a4.w};
                    S2[2*jj]   = __builtin_elementwise_fma(vsa2, a2a, S2[2*jj]);
                    S2[2*jj+1] = __builtin_elementwise_fma(vsa2, a2b, S2[2*jj+1]);
                    if (jj & 1) {
                        o1 = __builtin_elementwise_fma(S2[2*jj],   q2a, o1);
                        o3 = __builtin_elementwise_fma(S2[2*jj+1], q2b, o3);
                    } else {
                        o0  = __builtin_elementwise_fma(S2[2*jj],   q2a, o0);
                        o2v = __builtin_elementwise_fma(S2[2*jj+1], q2b, o2v);
                    }
                }
                f32x2 os = (o0 + o1) + (o2v + o3);

                const float rinv = 1.0f / (1.0f + rd);
                const float sr = s * rinv;
                Ob[tt * DH_ + lane] = (os.x + os.y) + sr * rq * vl;
                ci  = y * rinv;
                vsa = vl * sr;
            }
            __syncthreads();
        }
    }
}

// ---------------------------------------------------------------------------
// Kernel 3: out[bt][m] = sum_d O[bt][d] * Wo[m][d] + bo[m]
// ---------------------------------------------------------------------------
__global__ __launch_bounds__(256) void oproj_kernel(
    const float* __restrict__ O, const float* __restrict__ Wo,
    const float* __restrict__ bo, float* __restrict__ out)
{
    __shared__ __align__(16) float os[16][64];
    const int tid = threadIdx.x;
    const size_t t0 = (size_t)blockIdx.x * 16;
    {
        int tok = tid >> 4, dq = tid & 15;
        *(f32x4*)&os[tok][dq * 4] = *(const f32x4*)&O[(t0 + tok) * 64 + dq * 4];
    }
    __syncthreads();

    const int m = tid * 2;
    float acc0[16], acc1[16];
#pragma unroll
    for (int i = 0; i < 16; i++) { acc0[i] = 0.f; acc1[i] = 0.f; }

    const float* w0 = Wo + (size_t)m * 64;
    const float* w1 = w0 + 64;
#pragma unroll
    for (int dq = 0; dq < 16; ++dq) {
        f32x4 wa = *(const f32x4*)&w0[dq * 4];
        f32x4 wb = *(const f32x4*)&w1[dq * 4];
#pragma unroll
        for (int tok = 0; tok < 16; ++tok) {
            f32x4 o4 = *(const f32x4*)&os[tok][dq * 4];
            acc0[tok] = fmaf(o4.x, wa.x, fmaf(o4.y, wa.y,
                        fmaf(o4.z, wa.z, fmaf(o4.w, wa.w, acc0[tok]))));
            acc1[tok] = fmaf(o4.x, wb.x, fmaf(o4.y, wb.y,
                        fmaf(o4.z, wb.z, fmaf(o4.w, wb.w, acc1[tok]))));
        }
    }
    const float b0 = bo[m], b1 = bo[m + 1];
#pragma unroll
    for (int tok = 0; tok < 16; ++tok) {
        float2 v = make_float2(acc0[tok] + b0, acc1[tok] + b1);
        *(float2*)&out[(t0 + tok) * DM_ + m] = v;
    }
}

// ---------------------------------------------------------------------------
extern "C" void kernel_launch(void* const* d_in, const int* in_sizes, int n_in,
                              void* d_out, int out_size, void* d_ws, size_t ws_size,
                              hipStream_t stream)
{
    const float* x  = (const float*)d_in[0];
    const float* Wq = (const float*)d_in[1];
    const float* bq = (const float*)d_in[2];
    const float* Wk = (const float*)d_in[3];
    const float* bk = (const float*)d_in[4];
    const float* Wv = (const float*)d_in[5];
    const float* bv = (const float*)d_in[6];
    const float* Wo = (const float*)d_in[7];
    const float* bo = (const float*)d_in[8];
    float* out = (float*)d_out;

    // workspace: qkv [NTOK*192], O [NTOK*64], sbuf [NTOK]   (~34 MB)
    float* qkv  = (float*)d_ws;
    float* O    = qkv + (size_t)NTOK * 192;
    float* sbuf = O + (size_t)NTOK * 64;

    proj_kernel<<<NTOK / 64, 256, 0, stream>>>(x, Wq, bq, Wk, bk, Wv, bv, qkv);
    sdot_kernel<<<NTOK * 8 / 256, 256, 0, stream>>>(qkv, sbuf);
    scan_kernel<<<B_, 128, 0, stream>>>(qkv, sbuf, O);
    oproj_kernel<<<NTOK / 16, 256, 0, stream>>>(O, Wo, bo, out);
}

// Round 6
// 1590.108 us; speedup vs baseline: 1.5358x; 1.2388x over previous
//
#include <hip/hip_runtime.h>

#define B_   16
#define T_   2048
#define DM_  512
#define DH_  64
#define NTOK (B_ * T_)

typedef float f32x2 __attribute__((ext_vector_type(2)));
typedef float f32x4 __attribute__((ext_vector_type(4)));

// ---------------------------------------------------------------------------
// Full-wave (64-lane) sum via DPP, result uniform (SGPR-broadcast).
// row_shr 1/2/4/8 -> row sums in lanes 15/31/47/63; row_bcast15 + row_bcast31
// accumulate into lane 63; readlane 63 broadcasts.
// ctrl must be a compile-time constant -> template parameter.
// ---------------------------------------------------------------------------
template <int CTRL>
__device__ __forceinline__ float dpp_add_step(float acc) {
    int moved = __builtin_amdgcn_update_dpp(
        0, __builtin_bit_cast(int, acc), CTRL, 0xf, 0xf, true);
    return acc + __builtin_bit_cast(float, moved);
}
__device__ __forceinline__ float wave_sum_bcast(float x) {
    x = dpp_add_step<0x111>(x);  // row_shr:1
    x = dpp_add_step<0x112>(x);  // row_shr:2
    x = dpp_add_step<0x114>(x);  // row_shr:4
    x = dpp_add_step<0x118>(x);  // row_shr:8
    x = dpp_add_step<0x142>(x);  // row_bcast:15
    x = dpp_add_step<0x143>(x);  // row_bcast:31
    return __builtin_bit_cast(float,
        __builtin_amdgcn_readlane(__builtin_bit_cast(int, x), 63));
}

// ---------------------------------------------------------------------------
// Kernel 1: fused projection.  qkv[bt][0:64]=q, [64:128]=k, [128:192]=v
// ---------------------------------------------------------------------------
__global__ __launch_bounds__(256) void proj_kernel(
    const float* __restrict__ x,
    const float* __restrict__ Wq, const float* __restrict__ bq,
    const float* __restrict__ Wk, const float* __restrict__ bk,
    const float* __restrict__ Wv, const float* __restrict__ bvp,
    float* __restrict__ qkv)
{
    __shared__ __align__(16) float xs[32][64];    // [k][tok]
    __shared__ __align__(16) float ws[32][192];   // [k][d]
    const int tid = threadIdx.x;
    const int bt0 = blockIdx.x * 64;
    const int ty  = tid >> 4;
    const int tx  = tid & 15;

    f32x2 acc2[4][6];
#pragma unroll
    for (int i = 0; i < 4; i++)
#pragma unroll
        for (int j = 0; j < 6; j++) acc2[i][j] = (f32x2){0.f, 0.f};

    for (int kb = 0; kb < DM_; kb += 32) {
#pragma unroll
        for (int r = 0; r < 2; r++) {
            int idx = tid + r * 256;
            int tok = idx >> 3, kq = idx & 7;
            f32x4 xv = *(const f32x4*)&x[(size_t)(bt0 + tok) * DM_ + kb + kq * 4];
            xs[kq * 4 + 0][tok] = xv.x;
            xs[kq * 4 + 1][tok] = xv.y;
            xs[kq * 4 + 2][tok] = xv.z;
            xs[kq * 4 + 3][tok] = xv.w;
        }
#pragma unroll
        for (int r = 0; r < 6; r++) {
            int idx = tid + r * 256;
            int d = idx >> 3, kq = idx & 7;
            const float* wrow = (d < 64)  ? (Wq + (size_t)d * DM_)
                              : (d < 128) ? (Wk + (size_t)(d - 64) * DM_)
                                          : (Wv + (size_t)(d - 128) * DM_);
            f32x4 wv4 = *(const f32x4*)&wrow[kb + kq * 4];
            ws[kq * 4 + 0][d] = wv4.x;
            ws[kq * 4 + 1][d] = wv4.y;
            ws[kq * 4 + 2][d] = wv4.z;
            ws[kq * 4 + 3][d] = wv4.w;
        }
        __syncthreads();

#pragma unroll
        for (int kk = 0; kk < 32; kk++) {
            f32x4 x4 = *(const f32x4*)&xs[kk][ty * 4];
            const float xv[4] = {x4.x, x4.y, x4.z, x4.w};
            const f32x2* wsp = (const f32x2*)&ws[kk][tx * 12];
            f32x2 w2[6];
#pragma unroll
            for (int j2 = 0; j2 < 6; j2++) w2[j2] = wsp[j2];
#pragma unroll
            for (int i = 0; i < 4; i++) {
                f32x2 xb = {xv[i], xv[i]};
#pragma unroll
                for (int j2 = 0; j2 < 6; j2++)
                    acc2[i][j2] = __builtin_elementwise_fma(xb, w2[j2], acc2[i][j2]);
            }
        }
        __syncthreads();
    }

#pragma unroll
    for (int i = 0; i < 4; i++) {
        const int bt = bt0 + ty * 4 + i;
        float* dst = qkv + (size_t)bt * 192 + tx * 12;
#pragma unroll
        for (int j2 = 0; j2 < 6; j2++) {
            int c0 = tx * 12 + 2 * j2;
#pragma unroll
            for (int h = 0; h < 2; h++) {
                int c = c0 + h;
                float bias = (c < 64) ? bq[c] : (c < 128) ? bk[c - 64] : bvp[c - 128];
                dst[2 * j2 + h] = ((h == 0) ? acc2[i][j2].x : acc2[i][j2].y) + bias;
            }
        }
    }
}

// ---------------------------------------------------------------------------
// Kernel 1b: s[t] = q_t . k_t   (8 lanes per token)
// ---------------------------------------------------------------------------
__global__ __launch_bounds__(256) void sdot_kernel(
    const float* __restrict__ qkv, float* __restrict__ sbuf)
{
    const int tid = blockIdx.x * 256 + threadIdx.x;
    const int tok = tid >> 3, l = tid & 7;
    const float* row = qkv + (size_t)tok * 192 + l * 8;
    f32x4 qa = *(const f32x4*)row;
    f32x4 qb = *(const f32x4*)(row + 4);
    f32x4 ka = *(const f32x4*)(row + 64);
    f32x4 kb = *(const f32x4*)(row + 68);
    float r = qa.x * ka.x + qa.y * ka.y + qa.z * ka.z + qa.w * ka.w
            + qb.x * kb.x + qb.y * kb.y + qb.z * kb.z + qb.w * kb.w;
    r += __shfl_xor(r, 1, 64);
    r += __shfl_xor(r, 2, 64);
    r += __shfl_xor(r, 4, 64);
    if (l == 0) sbuf[tok] = r;
}

// ---------------------------------------------------------------------------
// Kernel 2: sequential scan, deferred-update form, merged inner loop.
//   wave 0 computes; wave 1 double-buffers qkv+s tiles.
// Per step t (updates from step t-1 folded into the single loop):
//   loop jj: A -= ci*aup ; y += A*k ; S += vsa*aup ; o' += S*q
//   rd = k.y, rq = q.y  (DPP reduce -> SGPR)
//   rinv = rcp(1+rd); o = o' + s*rinv*rq*v; ci = y*rinv; vsa = v*s*rinv
// ---------------------------------------------------------------------------
__global__ __launch_bounds__(128, 1) void scan_kernel(
    const float* __restrict__ qkv, const float* __restrict__ sbuf,
    float* __restrict__ O)
{
    __shared__ __align__(16) float stage[2][32 * 192];  // 2 x 24KB
    __shared__ __align__(16) float sst[2][32];
    __shared__ __align__(16) float au_sm[2][64];
    const int tid  = threadIdx.x;
    const int lane = tid & 63;
    const int w    = tid >> 6;
    const int b    = blockIdx.x;
    const float* src = qkv + (size_t)b * T_ * 192;
    const float* sb  = sbuf + (size_t)b * T_;
    float* Og = O + (size_t)b * T_ * DH_;

    if (w == 1) {  // prologue: stage block 0
#pragma unroll 2
        for (int r = 0; r < 24; r++)
            *(f32x4*)&stage[0][r * 256 + lane * 4] =
                *(const f32x4*)&src[r * 256 + lane * 4];
        if (lane < 8) ((f32x4*)sst[0])[lane] = ((const f32x4*)sb)[lane];
    } else {
        au_sm[0][lane] = 0.f;
        au_sm[1][lane] = 0.f;
    }
    __syncthreads();

    if (w == 1) {
        for (int blk = 0; blk < 64; ++blk) {
            if (blk + 1 < 64) {
                const float* s2 = src + (size_t)(blk + 1) * 6144;
                float* dst = stage[(blk + 1) & 1];
#pragma unroll 2
                for (int r = 0; r < 24; r++)
                    *(f32x4*)&dst[r * 256 + lane * 4] =
                        *(const f32x4*)&s2[r * 256 + lane * 4];
                if (lane < 8)
                    ((f32x4*)sst[(blk + 1) & 1])[lane] =
                        ((const f32x4*)(sb + (size_t)(blk + 1) * 32))[lane];
            }
            __syncthreads();
        }
    } else {
        f32x2 A2[32], S2[32];
#pragma unroll
        for (int m = 0; m < 32; m++) {
            A2[m].x = (2 * m == lane)     ? 1.f : 0.f;   // A0 = I
            A2[m].y = (2 * m + 1 == lane) ? 1.f : 0.f;
            S2[m] = (f32x2){0.f, 0.f};
        }
        float ci = 0.f, vsa = 0.f;

        for (int blk = 0; blk < 64; ++blk) {
            const float* stg = stage[blk & 1];
            const float* ss  = sst[blk & 1];
            float* Ob = Og + (size_t)blk * 32 * DH_;
            for (int tt = 0; tt < 32; ++tt) {
                const float* st = stg + tt * 192;
                const int cb = tt & 1;
                const float* aup = au_sm[cb ^ 1];   // y of step t-1 (broadcast)
                const float ql = st[lane];
                const float kl = st[64 + lane];
                const float vl = st[128 + lane];
                const float s  = ss[tt];
                const f32x2 nci2 = {-ci, -ci};
                const f32x2 vsa2 = {vsa, vsa};

                // merged loop: fold A,S updates of t-1; y = A k; o' = S q
                f32x2 y0 = {0,0}, y1 = {0,0}, y2s = {0,0}, y3 = {0,0};
                f32x2 o0 = {0,0}, o1 = {0,0}, o2s = {0,0}, o3 = {0,0};
#pragma unroll
                for (int jj = 0; jj < 16; jj++) {
                    f32x4 a4 = *(const f32x4*)&aup[jj * 4];
                    f32x4 k4 = *(const f32x4*)&st[64 + jj * 4];
                    f32x4 q4 = *(const f32x4*)&st[jj * 4];
                    f32x2 a2a = {a4.x, a4.y}, a2b = {a4.z, a4.w};
                    f32x2 k2a = {k4.x, k4.y}, k2b = {k4.z, k4.w};
                    f32x2 q2a = {q4.x, q4.y}, q2b = {q4.z, q4.w};
                    A2[2*jj]   = __builtin_elementwise_fma(nci2, a2a, A2[2*jj]);
                    A2[2*jj+1] = __builtin_elementwise_fma(nci2, a2b, A2[2*jj+1]);
                    S2[2*jj]   = __builtin_elementwise_fma(vsa2, a2a, S2[2*jj]);
                    S2[2*jj+1] = __builtin_elementwise_fma(vsa2, a2b, S2[2*jj+1]);
                    if (jj & 1) {
                        y1 = __builtin_elementwise_fma(A2[2*jj],   k2a, y1);
                        y3 = __builtin_elementwise_fma(A2[2*jj+1], k2b, y3);
                        o1 = __builtin_elementwise_fma(S2[2*jj],   q2a, o1);
                        o3 = __builtin_elementwise_fma(S2[2*jj+1], q2b, o3);
                    } else {
                        y0  = __builtin_elementwise_fma(A2[2*jj],   k2a, y0);
                        y2s = __builtin_elementwise_fma(A2[2*jj+1], k2b, y2s);
                        o0  = __builtin_elementwise_fma(S2[2*jj],   q2a, o0);
                        o2s = __builtin_elementwise_fma(S2[2*jj+1], q2b, o2s);
                    }
                }
                f32x2 ys = (y0 + y1) + (y2s + y3);
                const float y = ys.x + ys.y;
                au_sm[cb][lane] = y;                 // broadcast for step t+1

                // cross-lane reduces on VALU (DPP), results uniform in SGPR
                const float rd = wave_sum_bcast(kl * y);
                const float rq = wave_sum_bcast(ql * y);

                f32x2 os = (o0 + o1) + (o2s + o3);
                const float rinv = __builtin_amdgcn_rcpf(1.0f + rd);
                const float sr = s * rinv;
                Ob[tt * DH_ + lane] = (os.x + os.y) + sr * rq * vl;
                ci  = y * rinv;
                vsa = vl * sr;
            }
            __syncthreads();
        }
    }
}

// ---------------------------------------------------------------------------
// Kernel 3: out[bt][m] = sum_d O[bt][d] * Wo[m][d] + bo[m]
// ---------------------------------------------------------------------------
__global__ __launch_bounds__(256) void oproj_kernel(
    const float* __restrict__ O, const float* __restrict__ Wo,
    const float* __restrict__ bo, float* __restrict__ out)
{
    __shared__ __align__(16) float os[16][64];
    const int tid = threadIdx.x;
    const size_t t0 = (size_t)blockIdx.x * 16;
    {
        int tok = tid >> 4, dq = tid & 15;
        *(f32x4*)&os[tok][dq * 4] = *(const f32x4*)&O[(t0 + tok) * 64 + dq * 4];
    }
    __syncthreads();

    const int m = tid * 2;
    float acc0[16], acc1[16];
#pragma unroll
    for (int i = 0; i < 16; i++) { acc0[i] = 0.f; acc1[i] = 0.f; }

    const float* w0 = Wo + (size_t)m * 64;
    const float* w1 = w0 + 64;
#pragma unroll
    for (int dq = 0; dq < 16; ++dq) {
        f32x4 wa = *(const f32x4*)&w0[dq * 4];
        f32x4 wb = *(const f32x4*)&w1[dq * 4];
#pragma unroll
        for (int tok = 0; tok < 16; ++tok) {
            f32x4 o4 = *(const f32x4*)&os[tok][dq * 4];
            acc0[tok] = fmaf(o4.x, wa.x, fmaf(o4.y, wa.y,
                        fmaf(o4.z, wa.z, fmaf(o4.w, wa.w, acc0[tok]))));
            acc1[tok] = fmaf(o4.x, wb.x, fmaf(o4.y, wb.y,
                        fmaf(o4.z, wb.z, fmaf(o4.w, wb.w, acc1[tok]))));
        }
    }
    const float b0 = bo[m], b1 = bo[m + 1];
#pragma unroll
    for (int tok = 0; tok < 16; ++tok) {
        float2 v = make_float2(acc0[tok] + b0, acc1[tok] + b1);
        *(float2*)&out[(t0 + tok) * DM_ + m] = v;
    }
}

// ---------------------------------------------------------------------------
extern "C" void kernel_launch(void* const* d_in, const int* in_sizes, int n_in,
                              void* d_out, int out_size, void* d_ws, size_t ws_size,
                              hipStream_t stream)
{
    const float* x  = (const float*)d_in[0];
    const float* Wq = (const float*)d_in[1];
    const float* bq = (const float*)d_in[2];
    const float* Wk = (const float*)d_in[3];
    const float* bk = (const float*)d_in[4];
    const float* Wv = (const float*)d_in[5];
    const float* bv = (const float*)d_in[6];
    const float* Wo = (const float*)d_in[7];
    const float* bo = (const float*)d_in[8];
    float* out = (float*)d_out;

    float* qkv  = (float*)d_ws;
    float* O    = qkv + (size_t)NTOK * 192;
    float* sbuf = O + (size_t)NTOK * 64;

    proj_kernel<<<NTOK / 64, 256, 0, stream>>>(x, Wq, bq, Wk, bk, Wv, bv, qkv);
    sdot_kernel<<<NTOK * 8 / 256, 256, 0, stream>>>(qkv, sbuf);
    scan_kernel<<<B_, 128, 0, stream>>>(qkv, sbuf, O);
    oproj_kernel<<<NTOK / 16, 256, 0, stream>>>(O, Wo, bo, out);
}

// Round 7
// 1456.988 us; speedup vs baseline: 1.6761x; 1.0914x over previous
//
#include <hip/hip_runtime.h>

#define B_   16
#define T_   2048
#define DM_  512
#define DH_  64
#define NTOK (B_ * T_)
#define C_   32
#define NCH  (T_ / C_)

typedef float f32x2 __attribute__((ext_vector_type(2)));
typedef float f32x4 __attribute__((ext_vector_type(4)));

template <int CTRL>
__device__ __forceinline__ float dpp_add_step(float acc) {
    int moved = __builtin_amdgcn_update_dpp(
        0, __builtin_bit_cast(int, acc), CTRL, 0xf, 0xf, true);
    return acc + __builtin_bit_cast(float, moved);
}

// ---------------------------------------------------------------------------
// Kernel 1: fused projection.  qkv[bt][0:64]=q, [64:128]=k, [128:192]=v
// ---------------------------------------------------------------------------
__global__ __launch_bounds__(256) void proj_kernel(
    const float* __restrict__ x,
    const float* __restrict__ Wq, const float* __restrict__ bq,
    const float* __restrict__ Wk, const float* __restrict__ bk,
    const float* __restrict__ Wv, const float* __restrict__ bvp,
    float* __restrict__ qkv)
{
    __shared__ __align__(16) float xs[32][64];    // [k][tok]
    __shared__ __align__(16) float ws[32][192];   // [k][d]
    const int tid = threadIdx.x;
    const int bt0 = blockIdx.x * 64;
    const int ty  = tid >> 4;
    const int tx  = tid & 15;

    f32x2 acc2[4][6];
#pragma unroll
    for (int i = 0; i < 4; i++)
#pragma unroll
        for (int j = 0; j < 6; j++) acc2[i][j] = (f32x2){0.f, 0.f};

    for (int kb = 0; kb < DM_; kb += 32) {
#pragma unroll
        for (int r = 0; r < 2; r++) {
            int idx = tid + r * 256;
            int tok = idx >> 3, kq = idx & 7;
            f32x4 xv = *(const f32x4*)&x[(size_t)(bt0 + tok) * DM_ + kb + kq * 4];
            xs[kq * 4 + 0][tok] = xv.x;
            xs[kq * 4 + 1][tok] = xv.y;
            xs[kq * 4 + 2][tok] = xv.z;
            xs[kq * 4 + 3][tok] = xv.w;
        }
#pragma unroll
        for (int r = 0; r < 6; r++) {
            int idx = tid + r * 256;
            int d = idx >> 3, kq = idx & 7;
            const float* wrow = (d < 64)  ? (Wq + (size_t)d * DM_)
                              : (d < 128) ? (Wk + (size_t)(d - 64) * DM_)
                                          : (Wv + (size_t)(d - 128) * DM_);
            f32x4 wv4 = *(const f32x4*)&wrow[kb + kq * 4];
            ws[kq * 4 + 0][d] = wv4.x;
            ws[kq * 4 + 1][d] = wv4.y;
            ws[kq * 4 + 2][d] = wv4.z;
            ws[kq * 4 + 3][d] = wv4.w;
        }
        __syncthreads();

#pragma unroll
        for (int kk = 0; kk < 32; kk++) {
            f32x4 x4 = *(const f32x4*)&xs[kk][ty * 4];
            const float xv[4] = {x4.x, x4.y, x4.z, x4.w};
            const f32x2* wsp = (const f32x2*)&ws[kk][tx * 12];
            f32x2 w2[6];
#pragma unroll
            for (int j2 = 0; j2 < 6; j2++) w2[j2] = wsp[j2];
#pragma unroll
            for (int i = 0; i < 4; i++) {
                f32x2 xb = {xv[i], xv[i]};
#pragma unroll
                for (int j2 = 0; j2 < 6; j2++)
                    acc2[i][j2] = __builtin_elementwise_fma(xb, w2[j2], acc2[i][j2]);
            }
        }
        __syncthreads();
    }

#pragma unroll
    for (int i = 0; i < 4; i++) {
        const int bt = bt0 + ty * 4 + i;
        float* dst = qkv + (size_t)bt * 192 + tx * 12;
#pragma unroll
        for (int j2 = 0; j2 < 6; j2++) {
            int c0 = tx * 12 + 2 * j2;
#pragma unroll
            for (int h = 0; h < 2; h++) {
                int c = c0 + h;
                float bias = (c < 64) ? bq[c] : (c < 128) ? bk[c - 64] : bvp[c - 128];
                dst[2 * j2 + h] = ((h == 0) ? acc2[i][j2].x : acc2[i][j2].y) + bias;
            }
        }
    }
}

// ---------------------------------------------------------------------------
// Kernel 1b: s[t] = q_t . k_t   (8 lanes per token)
// ---------------------------------------------------------------------------
__global__ __launch_bounds__(256) void sdot_kernel(
    const float* __restrict__ qkv, float* __restrict__ sbuf)
{
    const int tid = blockIdx.x * 256 + threadIdx.x;
    const int tok = tid >> 3, l = tid & 7;
    const float* row = qkv + (size_t)tok * 192 + l * 8;
    f32x4 qa = *(const f32x4*)row;
    f32x4 qb = *(const f32x4*)(row + 4);
    f32x4 ka = *(const f32x4*)(row + 64);
    f32x4 kb = *(const f32x4*)(row + 68);
    float r = qa.x * ka.x + qa.y * ka.y + qa.z * ka.z + qa.w * ka.w
            + qb.x * kb.x + qb.y * kb.y + qb.z * kb.z + qb.w * kb.w;
    r += __shfl_xor(r, 1, 64);
    r += __shfl_xor(r, 2, 64);
    r += __shfl_xor(r, 4, 64);
    if (l == 0) sbuf[tok] = r;
}

// ---------------------------------------------------------------------------
// Kernel 2: chunked WY scan.  1 block (512 thr = 8 waves) per batch.
// Per chunk (C=32):
//   1a: W = A·K^T (LDS), Obase = S·Q (regs, DPP-reduced)
//   1b: G = W^T K (Gram, symmetric)
//   2 : 32-step forward elimination: d_t=1+G[t][t]; W[j>t]-=m_j W[t];
//       G[j>t]-=m_j G[t]  (W cols become z~_t)
//   2b: R = W^T Q   (z~_i . q_j)
//   3a: O[:,j] = Obase[:,j] + sum_{i<=j} (s_i/d_i) R[i][j] v_i
//   3b: A -= W^T diag(1/d) W ; S += v diag(s/d) W  (S in regs)
// ---------------------------------------------------------------------------
__global__ __launch_bounds__(512, 1) void scan_kernel(
    const float* __restrict__ qkv, const float* __restrict__ sbuf,
    float* __restrict__ O)
{
    __shared__ __align__(16) float A[64][68];
    __shared__ __align__(16) float KQV[3][32][68];   // [0]=K,[1]=Q,[2]=V
    __shared__ __align__(16) float W[32][68];
    __shared__ __align__(16) float GR[32][36];       // G during elim, R after
    __shared__ float dv[32], av[32], sv[32];

    const int tid = threadIdx.x;
    const int b   = blockIdx.x;
    const float* src = qkv + (size_t)b * T_ * 192;
    const float* sbp = sbuf + (size_t)b * T_;
    float* Og = O + (size_t)b * T_ * 64;

    const int jt  = tid >> 4;          // 0..31
    const int q16 = tid & 15;          // 0..15
    const int dow = tid >> 3;          // 0..63
    const int m0  = (tid & 7) * 8;     // S col slice
    const int jq  = tid & 7;           // j-quad for 3a
    const int j0q = jq * 4;

    f32x2 sreg[4] = {{0,0},{0,0},{0,0},{0,0}};   // S[dow][m0..m0+8)

    for (int e = tid; e < 64 * 68; e += 512) {
        int dd = e / 68, mm = e % 68;
        A[dd][mm] = (dd == mm) ? 1.f : 0.f;
    }
    __syncthreads();

    for (int c = 0; c < NCH; ++c) {
        // ---- stage chunk c ----
        {
            const float* s2 = src + (size_t)c * C_ * 192;
#pragma unroll
            for (int r = 0; r < 3; r++) {
                int idx = tid + r * 512;            // 0..1535
                int which = idx >> 9;               // 0..2
                int t = (idx >> 4) & 31;
                int dq = (idx & 15) * 4;
                int off = (which == 0) ? 64 : ((which == 1) ? 0 : 128);
                *(f32x4*)&KQV[which][t][dq] =
                    *(const f32x4*)&s2[(size_t)t * 192 + off + dq];
            }
            if (tid < 32) sv[tid] = sbp[c * C_ + tid];
        }
        __syncthreads();

        // ---- phase 1a ----
        float obase[4];
        {
            f32x2 wp0 = {0,0}, wp1 = {0,0}, wp2 = {0,0}, wp3 = {0,0};
#pragma unroll
            for (int mq = 0; mq < 16; ++mq) {
                f32x4 kv = *(const f32x4*)&KQV[0][jt][mq * 4];
                f32x2 k2a = {kv.x, kv.y}, k2b = {kv.z, kv.w};
                f32x4 a0 = *(const f32x4*)&A[q16     ][mq * 4];
                f32x4 a1 = *(const f32x4*)&A[q16 + 16][mq * 4];
                f32x4 a2 = *(const f32x4*)&A[q16 + 32][mq * 4];
                f32x4 a3 = *(const f32x4*)&A[q16 + 48][mq * 4];
                wp0 = __builtin_elementwise_fma((f32x2){a0.x,a0.y}, k2a, wp0);
                wp0 = __builtin_elementwise_fma((f32x2){a0.z,a0.w}, k2b, wp0);
                wp1 = __builtin_elementwise_fma((f32x2){a1.x,a1.y}, k2a, wp1);
                wp1 = __builtin_elementwise_fma((f32x2){a1.z,a1.w}, k2b, wp1);
                wp2 = __builtin_elementwise_fma((f32x2){a2.x,a2.y}, k2a, wp2);
                wp2 = __builtin_elementwise_fma((f32x2){a2.z,a2.w}, k2b, wp2);
                wp3 = __builtin_elementwise_fma((f32x2){a3.x,a3.y}, k2a, wp3);
                wp3 = __builtin_elementwise_fma((f32x2){a3.z,a3.w}, k2b, wp3);
            }
            W[jt][q16]      = wp0.x + wp0.y;
            W[jt][q16 + 16] = wp1.x + wp1.y;
            W[jt][q16 + 32] = wp2.x + wp2.y;
            W[jt][q16 + 48] = wp3.x + wp3.y;

            // S·Q partials over own m-slice, all 32 columns
            f32x2 part[32];
#pragma unroll
            for (int j = 0; j < 32; ++j) part[j] = (f32x2){0.f, 0.f};
#pragma unroll
            for (int j = 0; j < 32; ++j) {
                f32x4 qa = *(const f32x4*)&KQV[1][j][m0];
                f32x4 qb = *(const f32x4*)&KQV[1][j][m0 + 4];
                part[j] = __builtin_elementwise_fma(sreg[0], (f32x2){qa.x,qa.y}, part[j]);
                part[j] = __builtin_elementwise_fma(sreg[1], (f32x2){qa.z,qa.w}, part[j]);
                part[j] = __builtin_elementwise_fma(sreg[2], (f32x2){qb.x,qb.y}, part[j]);
                part[j] = __builtin_elementwise_fma(sreg[3], (f32x2){qb.z,qb.w}, part[j]);
            }
            // 8-lane butterfly reduce (d-group = tid&7), keep own j-quad
#pragma unroll
            for (int j = 0; j < 32; ++j) {
                float v = part[j].x + part[j].y;
                v = dpp_add_step<0x141>(v);  // row_half_mirror: s <-> 7-s
                v = dpp_add_step<0x1B>(v);   // quad_perm {3,2,1,0}
                v = dpp_add_step<0xB1>(v);   // quad_perm {1,0,3,2}
                if ((j >> 2) == jq) obase[j & 3] = v;
            }
        }
        __syncthreads();

        // ---- phase 1b: G ----
        {
            const int i = jt, jj0 = q16 * 2;
            f32x2 ga = {0,0}, gb = {0,0};
#pragma unroll
            for (int dq = 0; dq < 16; ++dq) {
                f32x4 w4 = *(const f32x4*)&W[i][dq * 4];
                f32x4 ka = *(const f32x4*)&KQV[0][jj0][dq * 4];
                f32x4 kb = *(const f32x4*)&KQV[0][jj0 + 1][dq * 4];
                ga = __builtin_elementwise_fma((f32x2){w4.x,w4.y}, (f32x2){ka.x,ka.y}, ga);
                ga = __builtin_elementwise_fma((f32x2){w4.z,w4.w}, (f32x2){ka.z,ka.w}, ga);
                gb = __builtin_elementwise_fma((f32x2){w4.x,w4.y}, (f32x2){kb.x,kb.y}, gb);
                gb = __builtin_elementwise_fma((f32x2){w4.z,w4.w}, (f32x2){kb.z,kb.w}, gb);
            }
            *(f32x2*)&GR[i][jj0] = (f32x2){ga.x + ga.y, gb.x + gb.y};
        }
        __syncthreads();

        // ---- phase 2: elimination ----
        for (int t = 0; t < C_; ++t) {
            const float rd = 1.0f / (1.0f + GR[t][t]);
            if (tid == 0) { dv[t] = rd; av[t] = sv[t] * rd; }
            const int j = t + 1 + jt;
            if (j < 32) {
                const float mj = GR[t][j] * rd;
                const int d4 = q16 * 4;
                f32x4 wt = *(const f32x4*)&W[t][d4];
                f32x4 wj = *(const f32x4*)&W[j][d4];
                wj.x -= mj * wt.x; wj.y -= mj * wt.y;
                wj.z -= mj * wt.z; wj.w -= mj * wt.w;
                *(f32x4*)&W[j][d4] = wj;
                if (q16 < 8) {
                    const int g4 = q16 * 4;
                    f32x4 gt = *(const f32x4*)&GR[t][g4];
                    f32x4 gj = *(const f32x4*)&GR[j][g4];
                    gj.x -= mj * gt.x; gj.y -= mj * gt.y;
                    gj.z -= mj * gt.z; gj.w -= mj * gt.w;
                    *(f32x4*)&GR[j][g4] = gj;
                }
            }
            __syncthreads();
        }

        // ---- phase 2b: R = W~^T Q ----
        {
            const int i = jt, jj0 = q16 * 2;
            f32x2 ra = {0,0}, rb = {0,0};
#pragma unroll
            for (int dq = 0; dq < 16; ++dq) {
                f32x4 w4 = *(const f32x4*)&W[i][dq * 4];
                f32x4 qa = *(const f32x4*)&KQV[1][jj0][dq * 4];
                f32x4 qb = *(const f32x4*)&KQV[1][jj0 + 1][dq * 4];
                ra = __builtin_elementwise_fma((f32x2){w4.x,w4.y}, (f32x2){qa.x,qa.y}, ra);
                ra = __builtin_elementwise_fma((f32x2){w4.z,w4.w}, (f32x2){qa.z,qa.w}, ra);
                rb = __builtin_elementwise_fma((f32x2){w4.x,w4.y}, (f32x2){qb.x,qb.y}, rb);
                rb = __builtin_elementwise_fma((f32x2){w4.z,w4.w}, (f32x2){qb.z,qb.w}, rb);
            }
            *(f32x2*)&GR[i][jj0] = (f32x2){ra.x + ra.y, rb.x + rb.y};
        }
        __syncthreads();

        // ---- phase 3a: O ----
        {
            f32x4 oacc = {obase[0], obase[1], obase[2], obase[3]};
            for (int i = 0; i < j0q; ++i) {
                const float cv = av[i] * KQV[2][i][dow];
                f32x4 r4 = *(const f32x4*)&GR[i][j0q];
                oacc.x += cv * r4.x; oacc.y += cv * r4.y;
                oacc.z += cv * r4.z; oacc.w += cv * r4.w;
            }
            {
                const float c0 = av[j0q + 0] * KQV[2][j0q + 0][dow];
                const float c1 = av[j0q + 1] * KQV[2][j0q + 1][dow];
                const float c2 = av[j0q + 2] * KQV[2][j0q + 2][dow];
                const float c3 = av[j0q + 3] * KQV[2][j0q + 3][dow];
                f32x4 r0 = *(const f32x4*)&GR[j0q + 0][j0q];
                f32x4 r1 = *(const f32x4*)&GR[j0q + 1][j0q];
                f32x4 r2 = *(const f32x4*)&GR[j0q + 2][j0q];
                f32x4 r3 = *(const f32x4*)&GR[j0q + 3][j0q];
                oacc.x += c0 * r0.x;
                oacc.y += c0 * r0.y + c1 * r1.y;
                oacc.z += c0 * r0.z + c1 * r1.z + c2 * r2.z;
                oacc.w += c0 * r0.w + c1 * r1.w + c2 * r2.w + c3 * r3.w;
            }
            float* op = &Og[((size_t)c * C_) * 64 + dow];
            op[(j0q + 0) * 64] = oacc.x;
            op[(j0q + 1) * 64] = oacc.y;
            op[(j0q + 2) * 64] = oacc.z;
            op[(j0q + 3) * 64] = oacc.w;
        }

        // ---- phase 3b: A -= W~ diag(1/d) W~^T ; S += V diag(s/d) W~ ----
        {
            f32x4 aa0 = *(const f32x4*)&A[dow][m0];
            f32x4 aa1 = *(const f32x4*)&A[dow][m0 + 4];
            for (int t = 0; t < C_; ++t) {
                const float ca = W[t][dow] * dv[t];
                const float cs = KQV[2][t][dow] * av[t];
                f32x4 w0 = *(const f32x4*)&W[t][m0];
                f32x4 w1 = *(const f32x4*)&W[t][m0 + 4];
                aa0.x -= ca * w0.x; aa0.y -= ca * w0.y;
                aa0.z -= ca * w0.z; aa0.w -= ca * w0.w;
                aa1.x -= ca * w1.x; aa1.y -= ca * w1.y;
                aa1.z -= ca * w1.z; aa1.w -= ca * w1.w;
                sreg[0] = __builtin_elementwise_fma((f32x2){cs,cs}, (f32x2){w0.x,w0.y}, sreg[0]);
                sreg[1] = __builtin_elementwise_fma((f32x2){cs,cs}, (f32x2){w0.z,w0.w}, sreg[1]);
                sreg[2] = __builtin_elementwise_fma((f32x2){cs,cs}, (f32x2){w1.x,w1.y}, sreg[2]);
                sreg[3] = __builtin_elementwise_fma((f32x2){cs,cs}, (f32x2){w1.z,w1.w}, sreg[3]);
            }
            *(f32x4*)&A[dow][m0]     = aa0;
            *(f32x4*)&A[dow][m0 + 4] = aa1;
        }
        __syncthreads();   // protects A writes + KQV restage next chunk
    }
}

// ---------------------------------------------------------------------------
// Kernel 3: out[bt][m] = sum_d O[bt][d] * Wo[m][d] + bo[m]
// ---------------------------------------------------------------------------
__global__ __launch_bounds__(256) void oproj_kernel(
    const float* __restrict__ O, const float* __restrict__ Wo,
    const float* __restrict__ bo, float* __restrict__ out)
{
    __shared__ __align__(16) float os[16][64];
    const int tid = threadIdx.x;
    const size_t t0 = (size_t)blockIdx.x * 16;
    {
        int tok = tid >> 4, dq = tid & 15;
        *(f32x4*)&os[tok][dq * 4] = *(const f32x4*)&O[(t0 + tok) * 64 + dq * 4];
    }
    __syncthreads();

    const int m = tid * 2;
    float acc0[16], acc1[16];
#pragma unroll
    for (int i = 0; i < 16; i++) { acc0[i] = 0.f; acc1[i] = 0.f; }

    const float* w0 = Wo + (size_t)m * 64;
    const float* w1 = w0 + 64;
#pragma unroll
    for (int dq = 0; dq < 16; ++dq) {
        f32x4 wa = *(const f32x4*)&w0[dq * 4];
        f32x4 wb = *(const f32x4*)&w1[dq * 4];
#pragma unroll
        for (int tok = 0; tok < 16; ++tok) {
            f32x4 o4 = *(const f32x4*)&os[tok][dq * 4];
            acc0[tok] = fmaf(o4.x, wa.x, fmaf(o4.y, wa.y,
                        fmaf(o4.z, wa.z, fmaf(o4.w, wa.w, acc0[tok]))));
            acc1[tok] = fmaf(o4.x, wb.x, fmaf(o4.y, wb.y,
                        fmaf(o4.z, wb.z, fmaf(o4.w, wb.w, acc1[tok]))));
        }
    }
    const float b0 = bo[m], b1 = bo[m + 1];
#pragma unroll
    for (int tok = 0; tok < 16; ++tok) {
        float2 v = make_float2(acc0[tok] + b0, acc1[tok] + b1);
        *(float2*)&out[(t0 + tok) * DM_ + m] = v;
    }
}

// ---------------------------------------------------------------------------
extern "C" void kernel_launch(void* const* d_in, const int* in_sizes, int n_in,
                              void* d_out, int out_size, void* d_ws, size_t ws_size,
                              hipStream_t stream)
{
    const float* x  = (const float*)d_in[0];
    const float* Wq = (const float*)d_in[1];
    const float* bq = (const float*)d_in[2];
    const float* Wk = (const float*)d_in[3];
    const float* bk = (const float*)d_in[4];
    const float* Wv = (const float*)d_in[5];
    const float* bv = (const float*)d_in[6];
    const float* Wo = (const float*)d_in[7];
    const float* bo = (const float*)d_in[8];
    float* out = (float*)d_out;

    float* qkv  = (float*)d_ws;
    float* O    = qkv + (size_t)NTOK * 192;
    float* sbuf = O + (size_t)NTOK * 64;

    proj_kernel<<<NTOK / 64, 256, 0, stream>>>(x, Wq, bq, Wk, bk, Wv, bv, qkv);
    sdot_kernel<<<NTOK * 8 / 256, 256, 0, stream>>>(qkv, sbuf);
    scan_kernel<<<B_, 512, 0, stream>>>(qkv, sbuf, O);
    oproj_kernel<<<NTOK / 16, 256, 0, stream>>>(O, Wo, bo, out);
}